// Round 1
// baseline (197.334 us; speedup 1.0000x reference)
//
#include <hip/hip_runtime.h>

#define T_LEN 192

// ---------------------------------------------------------------------------
// Generic tiled fp32 GEMM used for all 1x1 convs and the final xs@A matmul.
// Y[n, o0+.., t0+..] = sum_c W[o, c] * X[n, c, t] + B[o]
//   - W selected from 4 pointers by o0>>8 (fused 4x256-channel projection)
//   - wnstr: per-n stride of W rows (for batched W, i.e. xs in the final matmul)
// Tiles: 64(o) x 64(t) x 64(c); 256 threads; 4x4 micro-tile per thread.
// ---------------------------------------------------------------------------
template<int CIN>
__global__ __launch_bounds__(256) void gemm1x1_kernel(
    const float* __restrict__ W0, const float* __restrict__ W1,
    const float* __restrict__ W2, const float* __restrict__ W3,
    const float* __restrict__ B0, const float* __restrict__ B1,
    const float* __restrict__ B2, const float* __restrict__ B3,
    const float* __restrict__ X, float* __restrict__ Y,
    int cstr, int ostr, int wnstr)
{
  const int t0 = blockIdx.x * 64;
  const int o0 = blockIdx.y * 64;
  const int n  = blockIdx.z;
  const int sel = o0 >> 8;
  const float* W = sel == 0 ? W0 : sel == 1 ? W1 : sel == 2 ? W2 : W3;
  const float* B = sel == 0 ? B0 : sel == 1 ? B1 : sel == 2 ? B2 : B3;
  const int orow = o0 & 255;

  __shared__ float Ws[64][68];  // [c][o]  (transposed store, float4 reads)
  __shared__ float Xs[64][68];  // [c][t]

  const int tid = threadIdx.x;
  const int to = tid >> 4, tt = tid & 15;
  float acc[4][4] = {};

  for (int c0 = 0; c0 < CIN; c0 += 64) {
    __syncthreads();
#pragma unroll
    for (int l = 0; l < 4; ++l) {
      int idx = l * 256 + tid;
      int rr = idx >> 4, c4 = idx & 15;
      float4 wv = *reinterpret_cast<const float4*>(
          &W[(size_t)n * wnstr + (size_t)(orow + rr) * CIN + c0 + c4 * 4]);
      Ws[c4 * 4 + 0][rr] = wv.x; Ws[c4 * 4 + 1][rr] = wv.y;
      Ws[c4 * 4 + 2][rr] = wv.z; Ws[c4 * 4 + 3][rr] = wv.w;
      float4 xv = *reinterpret_cast<const float4*>(
          &X[((size_t)n * cstr + c0 + rr) * T_LEN + t0 + c4 * 4]);
      *reinterpret_cast<float4*>(&Xs[rr][c4 * 4]) = xv;
    }
    __syncthreads();
#pragma unroll
    for (int kk = 0; kk < 64; ++kk) {
      float4 a = *reinterpret_cast<const float4*>(&Ws[kk][to * 4]);
      float4 b = *reinterpret_cast<const float4*>(&Xs[kk][tt * 4]);
      acc[0][0] += a.x * b.x; acc[0][1] += a.x * b.y; acc[0][2] += a.x * b.z; acc[0][3] += a.x * b.w;
      acc[1][0] += a.y * b.x; acc[1][1] += a.y * b.y; acc[1][2] += a.y * b.z; acc[1][3] += a.y * b.w;
      acc[2][0] += a.z * b.x; acc[2][1] += a.z * b.y; acc[2][2] += a.z * b.z; acc[2][3] += a.z * b.w;
      acc[3][0] += a.w * b.x; acc[3][1] += a.w * b.y; acc[3][2] += a.w * b.z; acc[3][3] += a.w * b.w;
    }
  }
#pragma unroll
  for (int i = 0; i < 4; ++i) {
    float bi = B ? B[orow + to * 4 + i] : 0.f;
    float4 v = make_float4(acc[i][0] + bi, acc[i][1] + bi, acc[i][2] + bi, acc[i][3] + bi);
    *reinterpret_cast<float4*>(
        &Y[((size_t)n * ostr + o0 + to * 4 + i) * T_LEN + t0 + tt * 4]) = v;
  }
}

// ---------------------------------------------------------------------------
// Per-scale K-tap conv: k[n,o,t] = bk[o] + sum_{c<256,j<K} wk[o,c,j]*h[n,c,t+j-a]
// h staged in LDS with halo; 16(o) x 64(t) per block.
// ---------------------------------------------------------------------------
template<int A>
__device__ __forceinline__ void wkconv_body(
    const float* __restrict__ hall, const float* __restrict__ WK,
    const float* __restrict__ BK, float* __restrict__ kout,
    float* Hs, int n, int chbase, int t0, int o0, int tid)
{
  constexpr int K   = 2 * A + 1;
  constexpr int TW  = 64 + 2 * A;
  constexpr int TWP = TW + 2;
  const int to = tid >> 4, tt = tid & 15;
  float acc[4] = {0.f, 0.f, 0.f, 0.f};

  for (int c0 = 0; c0 < 256; c0 += 32) {
    __syncthreads();
    for (int idx = tid; idx < 32 * TW; idx += 256) {
      int c = idx / TW, col = idx - c * TW;
      int t = t0 - A + col;
      Hs[c * TWP + col] = (t >= 0 && t < T_LEN)
          ? hall[((size_t)n * 1024 + chbase + c0 + c) * T_LEN + t] : 0.f;
    }
    __syncthreads();
    const float* wrow = &WK[((size_t)(o0 + to) * 256 + c0) * K];
#pragma unroll 4
    for (int c = 0; c < 32; ++c) {
      float win[K + 3];
#pragma unroll
      for (int x = 0; x < K + 3; ++x) win[x] = Hs[c * TWP + tt * 4 + x];
#pragma unroll
      for (int j = 0; j < K; ++j) {
        float w = wrow[c * K + j];
        acc[0] += w * win[j + 0]; acc[1] += w * win[j + 1];
        acc[2] += w * win[j + 2]; acc[3] += w * win[j + 3];
      }
    }
  }
  const int o = o0 + to;
  const float b = BK[o];
  float4 v = make_float4(acc[0] + b, acc[1] + b, acc[2] + b, acc[3] + b);
  *reinterpret_cast<float4*>(&kout[((size_t)n * 128 + o) * T_LEN + t0 + tt * 4]) = v;
}

__global__ __launch_bounds__(256) void wkconv_all(
    const float* __restrict__ hall,
    const float* __restrict__ wk0, const float* __restrict__ bk0,
    const float* __restrict__ wk1, const float* __restrict__ bk1,
    const float* __restrict__ wk2, const float* __restrict__ bk2,
    float* __restrict__ kbuf)
{
  __shared__ float Hs[32 * 76];
  const int t0 = blockIdx.x * 64;
  const int o0 = blockIdx.y * 16;
  const int s  = blockIdx.z >> 3;
  const int n  = blockIdx.z & 7;
  const int tid = threadIdx.x;
  if (s == 0)      wkconv_body<1>(hall, wk0, bk0, kbuf,          Hs, n, 0,   t0, o0, tid);
  else if (s == 1) wkconv_body<3>(hall, wk1, bk1, kbuf + 196608, Hs, n, 256, t0, o0, tid);
  else             wkconv_body<5>(hall, wk2, bk2, kbuf + 393216, Hs, n, 512, t0, o0, tid);
}

// ---------------------------------------------------------------------------
// r_j[n,t] = sum_c wa[c,j] * k[n,c,t]   (collapses the 128-ch dim; rank-K form)
// ---------------------------------------------------------------------------
template<int K>
__device__ __forceinline__ void rproj_body(
    const float* __restrict__ kb, const float* __restrict__ wa,
    float* __restrict__ rout, int t)
{
  float acc[K];
#pragma unroll
  for (int j = 0; j < K; ++j) acc[j] = 0.f;
  for (int c = 0; c < 128; ++c) {
    float kv = kb[c * T_LEN + t];
#pragma unroll
    for (int j = 0; j < K; ++j) acc[j] += wa[c * K + j] * kv;
  }
#pragma unroll
  for (int j = 0; j < K; ++j) rout[j * T_LEN + t] = acc[j];
}

__global__ __launch_bounds__(192) void rproj_all(
    const float* __restrict__ kbuf,
    const float* __restrict__ wa0, const float* __restrict__ wa1,
    const float* __restrict__ wa2, float* __restrict__ rbuf)
{
  const int n = blockIdx.x, s = blockIdx.y, t = threadIdx.x;
  const float* kb = kbuf + ((size_t)s * 8 + n) * 128 * T_LEN;
  float* rout = rbuf + ((size_t)s * 8 + n) * 11 * T_LEN;
  if (s == 0)      rproj_body<3>(kb, wa0, rout, t);
  else if (s == 1) rproj_body<7>(kb, wa1, rout, t);
  else             rproj_body<11>(kb, wa2, rout, t);
}

// ---------------------------------------------------------------------------
// Per (n,u) column: build logits for 3 scales, softmax over t, accumulate.
// Stores At[n][u][t] (transposed A) for coalesced writes + fast final GEMM.
// ---------------------------------------------------------------------------
__global__ __launch_bounds__(192) void abuild_kernel(
    const float* __restrict__ rbuf,
    const float* __restrict__ ba0, const float* __restrict__ ba1,
    const float* __restrict__ ba2, float* __restrict__ At)
{
  const int u = blockIdx.x, n = blockIdx.y;
  const int t = threadIdx.x;
  const int lane = t & 63, wid = t >> 6;
  __shared__ float wred[3];
  float asum = 0.f;
  const float bav[3] = {ba0[0], ba1[0], ba2[0]};
  const int avals[3] = {1, 3, 5};

  for (int s = 0; s < 3; ++s) {
    const int a = avals[s], K = 2 * a + 1;
    const float* rs = rbuf + ((size_t)s * 8 + n) * 11 * T_LEN;
    float val = bav[s];
    for (int j = 0; j < K; ++j) {
      int tp = t + j - a;
      int d = tp - u;
      if (tp >= 0 && tp < T_LEN && d <= a && d >= -a) val += rs[j * T_LEN + tp];
    }
    // block max (3 waves)
    float m = val;
#pragma unroll
    for (int off = 32; off > 0; off >>= 1) m = fmaxf(m, __shfl_xor(m, off));
    if (lane == 0) wred[wid] = m;
    __syncthreads();
    m = fmaxf(fmaxf(wred[0], wred[1]), wred[2]);
    __syncthreads();
    float e = __expf(val - m);
    float sm = e;
#pragma unroll
    for (int off = 32; off > 0; off >>= 1) sm += __shfl_xor(sm, off);
    if (lane == 0) wred[wid] = sm;
    __syncthreads();
    float tot = wred[0] + wred[1] + wred[2];
    __syncthreads();
    asum += e / tot;
  }
  At[((size_t)n * T_LEN + u) * T_LEN + t] = asum;
}

// ---------------------------------------------------------------------------
// Grouped conv (groups=32, K=3) + ReLU. Reads hall ch 768.., writes ch 0..255.
// ---------------------------------------------------------------------------
__global__ void gconv_kernel(const float* hin, const float* __restrict__ w2,
                             const float* __restrict__ b2, float* hout)
{
  const int t  = threadIdx.x + blockIdx.x * 64;
  const int oc = threadIdx.y + blockIdx.y * 4;
  const int n  = blockIdx.z;
  const int g  = oc >> 3;
  float acc = b2[oc];
  for (int i = 0; i < 8; ++i) {
    const float* hrow = &hin[((size_t)n * 1024 + 768 + g * 8 + i) * T_LEN];
#pragma unroll
    for (int j = 0; j < 3; ++j) {
      int tt = t + j - 1;
      float hv = (tt >= 0 && tt < T_LEN) ? hrow[tt] : 0.f;
      acc += w2[((size_t)oc * 8 + i) * 3 + j] * hv;
    }
  }
  hout[((size_t)n * 1024 + oc) * T_LEN + t] = fmaxf(acc, 0.f);
}

// ---------------------------------------------------------------------------
// At[n][u][t] -> A[n][t][u]  (32x32 LDS transpose tiles)
// ---------------------------------------------------------------------------
__global__ void transpose_kernel(const float* __restrict__ At, float* __restrict__ Aout)
{
  __shared__ float tile[32][33];
  const int n = blockIdx.z;
  const int u0 = blockIdx.y * 32, t0 = blockIdx.x * 32;
  const int x = threadIdx.x, y = threadIdx.y;
  for (int yy = y; yy < 32; yy += 8)
    tile[yy][x] = At[((size_t)n * T_LEN + u0 + yy) * T_LEN + t0 + x];
  __syncthreads();
  for (int yy = y; yy < 32; yy += 8)
    Aout[((size_t)n * T_LEN + t0 + yy) * T_LEN + u0 + x] = tile[x][yy];
}

// ---------------------------------------------------------------------------
extern "C" void kernel_launch(void* const* d_in, const int* in_sizes, int n_in,
                              void* d_out, int out_size, void* d_ws, size_t ws_size,
                              hipStream_t stream)
{
  const float* x   = (const float*)d_in[0];
  const float* wp0 = (const float*)d_in[1];
  const float* bp0 = (const float*)d_in[2];
  const float* wk0 = (const float*)d_in[3];
  const float* bk0 = (const float*)d_in[4];
  const float* wa0 = (const float*)d_in[5];
  const float* ba0 = (const float*)d_in[6];
  const float* wp1 = (const float*)d_in[7];
  const float* bp1 = (const float*)d_in[8];
  const float* wk1 = (const float*)d_in[9];
  const float* bk1 = (const float*)d_in[10];
  const float* wa1 = (const float*)d_in[11];
  const float* ba1 = (const float*)d_in[12];
  const float* wp2 = (const float*)d_in[13];
  const float* bp2 = (const float*)d_in[14];
  const float* wk2 = (const float*)d_in[15];
  const float* bk2 = (const float*)d_in[16];
  const float* wa2 = (const float*)d_in[17];
  const float* ba2 = (const float*)d_in[18];
  const float* w1  = (const float*)d_in[19];
  const float* b1  = (const float*)d_in[20];
  const float* w2  = (const float*)d_in[21];
  const float* b2  = (const float*)d_in[22];
  const float* w3  = (const float*)d_in[23];
  const float* b3  = (const float*)d_in[24];

  float* ws   = (float*)d_ws;
  float* hall = ws;                          // [8][1024][192]   = 1,572,864
  float* kbuf = hall + 8 * 1024 * 192;       // [3][8][128][192] =   589,824
  float* rbuf = kbuf + 3 * 8 * 128 * 192;    // [3][8][11][192]  =    50,688
  float* At   = rbuf + 3 * 8 * 11 * 192;     // [8][192][192]    =   294,912
  float* xs   = kbuf;                        // overlay: kbuf dead after rproj
  float* out0 = (float*)d_out;               // [8][256][192]
  float* Aout = out0 + 8 * 256 * 192;        // [8][192][192]

  // 1) fused 1x1 projections: h0|h1|h2|hmain -> hall channels [0|256|512|768]
  gemm1x1_kernel<512><<<dim3(3, 16, 8), 256, 0, stream>>>(
      wp0, wp1, wp2, w1, bp0, bp1, bp2, b1, x, hall, 512, 1024, 0);
  // 2) per-scale K-tap convs -> kbuf
  wkconv_all<<<dim3(3, 8, 24), 256, 0, stream>>>(
      hall, wk0, bk0, wk1, bk1, wk2, bk2, kbuf);
  // 3) collapse channel dim: r_j[n,t]
  rproj_all<<<dim3(8, 3), 192, 0, stream>>>(kbuf, wa0, wa1, wa2, rbuf);
  // 4) banded logits + column softmax, 3 scales summed -> At (transposed A)
  abuild_kernel<<<dim3(192, 8), 192, 0, stream>>>(rbuf, ba0, ba1, ba2, At);
  // 5) A output (transpose At)
  transpose_kernel<<<dim3(6, 6, 8), dim3(32, 8), 0, stream>>>(At, Aout);
  // 6) grouped conv + relu: hall ch768.. -> hall ch0..255 (h_s sections dead)
  gconv_kernel<<<dim3(3, 64, 8), dim3(64, 4), 0, stream>>>(hall, w2, b2, hall);
  // 7) w3 1x1: xs (overlaid on kbuf)
  gemm1x1_kernel<256><<<dim3(3, 4, 8), 256, 0, stream>>>(
      w3, w3, w3, w3, b3, b3, b3, b3, hall, xs, 1024, 256, 0);
  // 8) out0 = xs @ A  (reads Aout as the [t][u] operand)
  gemm1x1_kernel<192><<<dim3(3, 4, 8), 256, 0, stream>>>(
      xs, xs, xs, xs, nullptr, nullptr, nullptr, nullptr,
      Aout, out0, 192, 256, 256 * 192);
}

// Round 2
// 194.373 us; speedup vs baseline: 1.0152x; 1.0152x over previous
//
#include <hip/hip_runtime.h>

#define T_LEN 192

// ---------------------------------------------------------------------------
// Tiled fp32 GEMM for 1x1 convs and the final xs@A matmul.
// Y[n, o0+.., t0+..] = sum_c W[o, c] * X[n, c, t] + B[o]
// Tiles: 64(o) x 64(t) x 64(c); 256 threads; 4x4 micro-tile per thread.
// ---------------------------------------------------------------------------
template<int CIN>
__global__ __launch_bounds__(256) void gemm1x1_kernel(
    const float* __restrict__ W, const float* __restrict__ B,
    const float* __restrict__ X, float* __restrict__ Y,
    int cstr, int ostr, int wnstr)
{
  const int t0 = blockIdx.x * 64;
  const int o0 = blockIdx.y * 64;
  const int n  = blockIdx.z;

  __shared__ float Ws[64][68];  // [c][o]
  __shared__ float Xs[64][68];  // [c][t]

  const int tid = threadIdx.x;
  const int to = tid >> 4, tt = tid & 15;
  float acc[4][4] = {};

  for (int c0 = 0; c0 < CIN; c0 += 64) {
    __syncthreads();
#pragma unroll
    for (int l = 0; l < 4; ++l) {
      int idx = l * 256 + tid;
      int rr = idx >> 4, c4 = idx & 15;
      float4 wv = *reinterpret_cast<const float4*>(
          &W[(size_t)n * wnstr + (size_t)(o0 + rr) * CIN + c0 + c4 * 4]);
      Ws[c4 * 4 + 0][rr] = wv.x; Ws[c4 * 4 + 1][rr] = wv.y;
      Ws[c4 * 4 + 2][rr] = wv.z; Ws[c4 * 4 + 3][rr] = wv.w;
      float4 xv = *reinterpret_cast<const float4*>(
          &X[((size_t)n * cstr + c0 + rr) * T_LEN + t0 + c4 * 4]);
      *reinterpret_cast<float4*>(&Xs[rr][c4 * 4]) = xv;
    }
    __syncthreads();
#pragma unroll
    for (int kk = 0; kk < 64; ++kk) {
      float4 a = *reinterpret_cast<const float4*>(&Ws[kk][to * 4]);
      float4 b = *reinterpret_cast<const float4*>(&Xs[kk][tt * 4]);
      acc[0][0] += a.x * b.x; acc[0][1] += a.x * b.y; acc[0][2] += a.x * b.z; acc[0][3] += a.x * b.w;
      acc[1][0] += a.y * b.x; acc[1][1] += a.y * b.y; acc[1][2] += a.y * b.z; acc[1][3] += a.y * b.w;
      acc[2][0] += a.z * b.x; acc[2][1] += a.z * b.y; acc[2][2] += a.z * b.z; acc[2][3] += a.z * b.w;
      acc[3][0] += a.w * b.x; acc[3][1] += a.w * b.y; acc[3][2] += a.w * b.z; acc[3][3] += a.w * b.w;
    }
  }
#pragma unroll
  for (int i = 0; i < 4; ++i) {
    float bi = B ? B[o0 + to * 4 + i] : 0.f;
    float4 v = make_float4(acc[i][0] + bi, acc[i][1] + bi, acc[i][2] + bi, acc[i][3] + bi);
    *reinterpret_cast<float4*>(
        &Y[((size_t)n * ostr + o0 + to * 4 + i) * T_LEN + t0 + tt * 4]) = v;
  }
}

// ---------------------------------------------------------------------------
// Weight-folding precompute (per call; cheap).
// WKA[j,i,c'] = sum_{c<128} wa[c,j] * wk[c,c',i]          ([K*K][256], per scale)
// cka[j]     = sum_{c<128} wa[c,j] * bk[c]
// ---------------------------------------------------------------------------
template<int K>
__device__ __forceinline__ void wka_body(
    const float* __restrict__ wa, const float* __restrict__ wk,
    const float* __restrict__ bk, float* __restrict__ WKA,
    float* __restrict__ cka, int ji, int tid)
{
  if (ji >= K * K) return;
  const int j = ji / K, i = ji - j * K;
  float acc = 0.f;
  for (int c = 0; c < 128; ++c)
    acc += wa[c * K + j] * wk[((size_t)(c * 256 + tid)) * K + i];
  WKA[(size_t)ji * 256 + tid] = acc;
  if (i == 0 && tid == 0) {
    float s = 0.f;
    for (int c = 0; c < 128; ++c) s += wa[c * K + j] * bk[c];
    cka[j] = s;
  }
}

__global__ __launch_bounds__(256) void wka_kernel(
    const float* wa0, const float* wk0, const float* bk0,
    const float* wa1, const float* wk1, const float* bk1,
    const float* wa2, const float* wk2, const float* bk2,
    float* WKA, float* cka)
{
  const int s = blockIdx.y, ji = blockIdx.x, tid = threadIdx.x;
  float* wkap = WKA + (size_t)s * 121 * 256;
  float* ckap = cka + s * 11;
  if (s == 0)      wka_body<3>(wa0, wk0, bk0, wkap, ckap, ji, tid);
  else if (s == 1) wka_body<7>(wa1, wk1, bk1, wkap, ckap, ji, tid);
  else             wka_body<11>(wa2, wk2, bk2, wkap, ckap, ji, tid);
}

// ---------------------------------------------------------------------------
// WXA[cin][i][j] = sum_{c'<256} WKA[j,i,c'] * wp[c',cin]  ([512][K][K], per scale)
// bpA[j][i]     = sum_{c'<256} WKA[j,i,c'] * bp[c']
// ---------------------------------------------------------------------------
template<int K>
__device__ __forceinline__ void wxa_body(
    const float* __restrict__ WKA, const float* __restrict__ wp,
    const float* __restrict__ bp, float* __restrict__ WXA,
    float* __restrict__ bpA, int ji, int tid)
{
  if (ji >= K * K) return;
  const int j = ji / K, i = ji - j * K;
  const float* row = &WKA[(size_t)ji * 256];
  float acc = 0.f;
  for (int c = 0; c < 256; ++c) acc += row[c] * wp[(size_t)c * 512 + tid];
  WXA[((size_t)tid * K + i) * K + j] = acc;
  if (tid == 0) {
    float s = 0.f;
    for (int c = 0; c < 256; ++c) s += row[c] * bp[c];
    bpA[j * 11 + i] = s;
  }
}

__global__ __launch_bounds__(512) void wxa_kernel(
    const float* WKA,
    const float* wp0, const float* bp0,
    const float* wp1, const float* bp1,
    const float* wp2, const float* bp2,
    float* WXA, float* bpA)
{
  const int s = blockIdx.y, ji = blockIdx.x, tid = threadIdx.x;
  const float* wkap = WKA + (size_t)s * 121 * 256;
  float* wxap = WXA + (size_t)s * 512 * 121;
  float* bpap = bpA + s * 121;
  if (s == 0)      wxa_body<3>(wkap, wp0, bp0, wxap, bpap, ji, tid);
  else if (s == 1) wxa_body<7>(wkap, wp1, bp1, wxap, bpap, ji, tid);
  else             wxa_body<11>(wkap, wp2, bp2, wxap, bpap, ji, tid);
}

// ---------------------------------------------------------------------------
// Banded conv directly on x: per (scale, n, 64-channel chunk) partial sums
// rpart[s][n][cc][j][t] = sum_{c in chunk, i} WXA[c,i,j] * xpad[n,c,t+i-A]
// 192 threads (one per t); x chunk staged in LDS with halo, zeroed outside.
// ---------------------------------------------------------------------------
template<int A>
__device__ __forceinline__ void rcomp_body(
    const float* __restrict__ x, const float* __restrict__ WXA,
    float* __restrict__ rpart, float* Xs, int cc, int n, int t)
{
  constexpr int K  = 2 * A + 1;
  constexpr int W  = 192 + 2 * A;
  constexpr int WP = W + 2;
  float acc[K];
#pragma unroll
  for (int j = 0; j < K; ++j) acc[j] = 0.f;

  for (int sub = 0; sub < 4; ++sub) {
    const int c0 = cc * 64 + sub * 16;
    __syncthreads();
    for (int idx = t; idx < 16 * W; idx += 192) {
      int c = idx / W, p = idx - c * W;
      int tau = p - A;
      Xs[c * WP + p] = (tau >= 0 && tau < 192)
          ? x[((size_t)n * 512 + c0 + c) * 192 + tau] : 0.f;
    }
    __syncthreads();
    for (int c = 0; c < 16; ++c) {
      const float* wrow = &WXA[(size_t)(c0 + c) * K * K];
#pragma unroll
      for (int i = 0; i < K; ++i) {
        float xv = Xs[c * WP + t + i];
#pragma unroll
        for (int j = 0; j < K; ++j) acc[j] += wrow[i * K + j] * xv;
      }
    }
  }
#pragma unroll
  for (int j = 0; j < K; ++j)
    rpart[((size_t)((n * 8 + cc) * 11) + j) * 192 + t] = acc[j];
}

__global__ __launch_bounds__(192) void rcomp_kernel(
    const float* __restrict__ x, const float* __restrict__ WXA,
    float* __restrict__ rpart)
{
  __shared__ float Xs[16 * 204];
  const int cc = blockIdx.x, n = blockIdx.y, s = blockIdx.z;
  const int t = threadIdx.x;
  const float* wxap = WXA + (size_t)s * 512 * 121;
  float* rp = rpart + (size_t)s * 8 * 8 * 11 * 192;
  if (s == 0)      rcomp_body<1>(x, wxap, rp, Xs, cc, n, t);
  else if (s == 1) rcomp_body<3>(x, wxap, rp, Xs, cc, n, t);
  else             rcomp_body<5>(x, wxap, rp, Xs, cc, n, t);
}

// ---------------------------------------------------------------------------
// rbuf[s][n][j][t] = sum_cc rpart + cka[j] + sum_i 1[0<=t+i-A<T]*bpA[j,i]
// ---------------------------------------------------------------------------
__global__ __launch_bounds__(192) void rreduce_kernel(
    const float* __restrict__ rpart, const float* __restrict__ cka,
    const float* __restrict__ bpA, float* __restrict__ rbuf)
{
  const int n = blockIdx.x, s = blockIdx.y, t = threadIdx.x;
  const int A = (s == 0) ? 1 : (s == 1) ? 3 : 5;
  const int K = 2 * A + 1;
  const float* rp = rpart + (size_t)s * 8 * 8 * 11 * 192;
  for (int j = 0; j < K; ++j) {
    float acc = cka[s * 11 + j];
    for (int cc = 0; cc < 8; ++cc)
      acc += rp[((size_t)((n * 8 + cc) * 11) + j) * 192 + t];
    for (int i = 0; i < K; ++i) {
      int tau = t + i - A;
      if (tau >= 0 && tau < 192) acc += bpA[s * 121 + j * 11 + i];
    }
    rbuf[((size_t)(s * 8 + n) * 11 + j) * 192 + t] = acc;
  }
}

// ---------------------------------------------------------------------------
// Per (n,u) column: banded logits for 3 scales, softmax over t, summed.
// Stores At[n][u][t] (transposed A). 2 barriers total (merged reductions).
// ---------------------------------------------------------------------------
template<int A>
__device__ __forceinline__ float gather_val(const float* __restrict__ rs,
                                            int t, int u)
{
  constexpr int K = 2 * A + 1;
  float val = 0.f;
#pragma unroll
  for (int j = 0; j < K; ++j) {
    int tp = t + j - A;
    int d = tp - u;
    if (tp >= 0 && tp < 192 && d <= A && d >= -A) val += rs[j * 192 + tp];
  }
  return val;
}

__global__ __launch_bounds__(192) void abuild_kernel(
    const float* __restrict__ rbuf,
    const float* __restrict__ ba0, const float* __restrict__ ba1,
    const float* __restrict__ ba2, float* __restrict__ At)
{
  const int u = blockIdx.x, n = blockIdx.y;
  const int t = threadIdx.x;
  const int lane = t & 63, wid = t >> 6;
  __shared__ float wm[3][3], wsm[3][3];

  float v0 = ba0[0] + gather_val<1>(rbuf + (size_t)(0 * 8 + n) * 11 * 192, t, u);
  float v1 = ba1[0] + gather_val<3>(rbuf + (size_t)(1 * 8 + n) * 11 * 192, t, u);
  float v2 = ba2[0] + gather_val<5>(rbuf + (size_t)(2 * 8 + n) * 11 * 192, t, u);

  float m0 = v0, m1 = v1, m2 = v2;
#pragma unroll
  for (int off = 32; off > 0; off >>= 1) {
    m0 = fmaxf(m0, __shfl_xor(m0, off));
    m1 = fmaxf(m1, __shfl_xor(m1, off));
    m2 = fmaxf(m2, __shfl_xor(m2, off));
  }
  if (lane == 0) { wm[wid][0] = m0; wm[wid][1] = m1; wm[wid][2] = m2; }
  __syncthreads();
  m0 = fmaxf(fmaxf(wm[0][0], wm[1][0]), wm[2][0]);
  m1 = fmaxf(fmaxf(wm[0][1], wm[1][1]), wm[2][1]);
  m2 = fmaxf(fmaxf(wm[0][2], wm[1][2]), wm[2][2]);

  float e0 = __expf(v0 - m0), e1 = __expf(v1 - m1), e2 = __expf(v2 - m2);
  float s0 = e0, s1 = e1, s2 = e2;
#pragma unroll
  for (int off = 32; off > 0; off >>= 1) {
    s0 += __shfl_xor(s0, off);
    s1 += __shfl_xor(s1, off);
    s2 += __shfl_xor(s2, off);
  }
  if (lane == 0) { wsm[wid][0] = s0; wsm[wid][1] = s1; wsm[wid][2] = s2; }
  __syncthreads();
  s0 = wsm[0][0] + wsm[1][0] + wsm[2][0];
  s1 = wsm[0][1] + wsm[1][1] + wsm[2][1];
  s2 = wsm[0][2] + wsm[1][2] + wsm[2][2];

  At[((size_t)n * 192 + u) * 192 + t] = e0 / s0 + e1 / s1 + e2 / s2;
}

// ---------------------------------------------------------------------------
// Grouped conv (groups=32, K=3) + ReLU. hall ch0..255 (h1) -> ch256..511 (h2).
// ---------------------------------------------------------------------------
__global__ void gconv_kernel(const float* hin, const float* __restrict__ w2,
                             const float* __restrict__ b2, float* hout)
{
  const int t  = threadIdx.x + blockIdx.x * 64;
  const int oc = threadIdx.y + blockIdx.y * 4;
  const int n  = blockIdx.z;
  const int g  = oc >> 3;
  float acc = b2[oc];
  for (int i = 0; i < 8; ++i) {
    const float* hrow = &hin[((size_t)n * 512 + g * 8 + i) * 192];
#pragma unroll
    for (int j = 0; j < 3; ++j) {
      int tt = t + j - 1;
      float hv = (tt >= 0 && tt < 192) ? hrow[tt] : 0.f;
      acc += w2[((size_t)oc * 8 + i) * 3 + j] * hv;
    }
  }
  hout[((size_t)n * 512 + 256 + oc) * 192 + t] = fmaxf(acc, 0.f);
}

// ---------------------------------------------------------------------------
// At[n][u][t] -> A[n][t][u]
// ---------------------------------------------------------------------------
__global__ void transpose_kernel(const float* __restrict__ At, float* __restrict__ Aout)
{
  __shared__ float tile[32][33];
  const int n = blockIdx.z;
  const int u0 = blockIdx.y * 32, t0 = blockIdx.x * 32;
  const int xx = threadIdx.x, y = threadIdx.y;
  for (int yy = y; yy < 32; yy += 8)
    tile[yy][xx] = At[((size_t)n * 192 + u0 + yy) * 192 + t0 + xx];
  __syncthreads();
  for (int yy = y; yy < 32; yy += 8)
    Aout[((size_t)n * 192 + t0 + yy) * 192 + u0 + xx] = tile[xx][yy];
}

// ---------------------------------------------------------------------------
extern "C" void kernel_launch(void* const* d_in, const int* in_sizes, int n_in,
                              void* d_out, int out_size, void* d_ws, size_t ws_size,
                              hipStream_t stream)
{
  const float* x   = (const float*)d_in[0];
  const float* wp0 = (const float*)d_in[1];
  const float* bp0 = (const float*)d_in[2];
  const float* wk0 = (const float*)d_in[3];
  const float* bk0 = (const float*)d_in[4];
  const float* wa0 = (const float*)d_in[5];
  const float* ba0 = (const float*)d_in[6];
  const float* wp1 = (const float*)d_in[7];
  const float* bp1 = (const float*)d_in[8];
  const float* wk1 = (const float*)d_in[9];
  const float* bk1 = (const float*)d_in[10];
  const float* wa1 = (const float*)d_in[11];
  const float* ba1 = (const float*)d_in[12];
  const float* wp2 = (const float*)d_in[13];
  const float* bp2 = (const float*)d_in[14];
  const float* wk2 = (const float*)d_in[15];
  const float* bk2 = (const float*)d_in[16];
  const float* wa2 = (const float*)d_in[17];
  const float* ba2 = (const float*)d_in[18];
  const float* w1  = (const float*)d_in[19];
  const float* b1  = (const float*)d_in[20];
  const float* w2  = (const float*)d_in[21];
  const float* b2  = (const float*)d_in[22];
  const float* w3  = (const float*)d_in[23];
  const float* b3  = (const float*)d_in[24];

  float* ws   = (float*)d_ws;
  float* hall  = ws;                          // [8][512][192]      = 786,432
  float* At    = hall  + 786432;              // [8][192][192]      = 294,912
  float* xs    = At    + 294912;              // [8][256][192]      = 393,216
  float* rpart = xs    + 393216;              // [3][8][8][11][192] = 405,504
  float* rbuf  = rpart + 405504;              // [3][8][11][192]    =  50,688
  float* WKA   = rbuf  + 50688;               // [3][121][256]      =  92,928
  float* WXA   = WKA   + 92928;               // [3][512][121]      = 185,856
  float* bpA   = WXA   + 185856;              // [3][121]           =     384 (padded)
  float* cka   = bpA   + 384;                 // [3][11]            =      48
  float* out0  = (float*)d_out;               // [8][256][192]
  float* Aout  = out0 + 8 * 256 * 192;        // [8][192][192]

  // --- weight folding (per call) ---
  wka_kernel<<<dim3(121, 3), 256, 0, stream>>>(
      wa0, wk0, bk0, wa1, wk1, bk1, wa2, wk2, bk2, WKA, cka);
  wxa_kernel<<<dim3(121, 3), 512, 0, stream>>>(
      WKA, wp0, bp0, wp1, bp1, wp2, bp2, WXA, bpA);

  // --- main path h1 = w1 @ x ---
  gemm1x1_kernel<512><<<dim3(3, 4, 8), 256, 0, stream>>>(
      w1, b1, x, hall, 512, 512, 0);

  // --- banded r directly from x ---
  rcomp_kernel<<<dim3(8, 8, 3), 192, 0, stream>>>(x, WXA, rpart);
  rreduce_kernel<<<dim3(8, 3), 192, 0, stream>>>(rpart, cka, bpA, rbuf);

  // --- A build + transpose ---
  abuild_kernel<<<dim3(192, 8), 192, 0, stream>>>(rbuf, ba0, ba1, ba2, At);
  transpose_kernel<<<dim3(6, 6, 8), dim3(32, 8), 0, stream>>>(At, Aout);

  // --- main path tail ---
  gconv_kernel<<<dim3(3, 64, 8), dim3(64, 4), 0, stream>>>(hall, w2, b2, hall);
  gemm1x1_kernel<256><<<dim3(3, 4, 8), 256, 0, stream>>>(
      w3, b3, hall + 256 * 192, xs, 512, 256, 0);
  gemm1x1_kernel<192><<<dim3(3, 4, 8), 256, 0, stream>>>(
      xs, nullptr, Aout, out0, 192, 256, 256 * 192);
}

// Round 3
// 123.761 us; speedup vs baseline: 1.5945x; 1.5706x over previous
//
#include <hip/hip_runtime.h>

#define T_LEN 192

// ---------------------------------------------------------------------------
// Tiled fp32 GEMM for 1x1 convs and the final xs@A matmul.
// Y[n, o0+.., t0+..] = sum_c W[o, c] * X[n, c, t] + B[o]
// Tiles: 64(o) x 64(t) x 64(c); 256 threads; 4x4 micro-tile per thread.
// ---------------------------------------------------------------------------
template<int CIN>
__global__ __launch_bounds__(256) void gemm1x1_kernel(
    const float* __restrict__ W, const float* __restrict__ B,
    const float* __restrict__ X, float* __restrict__ Y,
    int cstr, int ostr, int wnstr)
{
  const int t0 = blockIdx.x * 64;
  const int o0 = blockIdx.y * 64;
  const int n  = blockIdx.z;

  __shared__ float Ws[64][68];  // [c][o]
  __shared__ float Xs[64][68];  // [c][t]

  const int tid = threadIdx.x;
  const int to = tid >> 4, tt = tid & 15;
  float acc[4][4] = {};

  for (int c0 = 0; c0 < CIN; c0 += 64) {
    __syncthreads();
#pragma unroll
    for (int l = 0; l < 4; ++l) {
      int idx = l * 256 + tid;
      int rr = idx >> 4, c4 = idx & 15;
      float4 wv = *reinterpret_cast<const float4*>(
          &W[(size_t)n * wnstr + (size_t)(o0 + rr) * CIN + c0 + c4 * 4]);
      Ws[c4 * 4 + 0][rr] = wv.x; Ws[c4 * 4 + 1][rr] = wv.y;
      Ws[c4 * 4 + 2][rr] = wv.z; Ws[c4 * 4 + 3][rr] = wv.w;
      float4 xv = *reinterpret_cast<const float4*>(
          &X[((size_t)n * cstr + c0 + rr) * T_LEN + t0 + c4 * 4]);
      *reinterpret_cast<float4*>(&Xs[rr][c4 * 4]) = xv;
    }
    __syncthreads();
#pragma unroll
    for (int kk = 0; kk < 64; ++kk) {
      float4 a = *reinterpret_cast<const float4*>(&Ws[kk][to * 4]);
      float4 b = *reinterpret_cast<const float4*>(&Xs[kk][tt * 4]);
      acc[0][0] += a.x * b.x; acc[0][1] += a.x * b.y; acc[0][2] += a.x * b.z; acc[0][3] += a.x * b.w;
      acc[1][0] += a.y * b.x; acc[1][1] += a.y * b.y; acc[1][2] += a.y * b.z; acc[1][3] += a.y * b.w;
      acc[2][0] += a.z * b.x; acc[2][1] += a.z * b.y; acc[2][2] += a.z * b.z; acc[2][3] += a.z * b.w;
      acc[3][0] += a.w * b.x; acc[3][1] += a.w * b.y; acc[3][2] += a.w * b.z; acc[3][3] += a.w * b.w;
    }
  }
#pragma unroll
  for (int i = 0; i < 4; ++i) {
    float bi = B ? B[o0 + to * 4 + i] : 0.f;
    float4 v = make_float4(acc[i][0] + bi, acc[i][1] + bi, acc[i][2] + bi, acc[i][3] + bi);
    *reinterpret_cast<float4*>(
        &Y[((size_t)n * ostr + o0 + to * 4 + i) * T_LEN + t0 + tt * 4]) = v;
  }
}

// ---------------------------------------------------------------------------
// Weight folding stage 1:
// WKA[j,i,c'] = sum_{c<128} wa[c,j] * wk[c,c',i]   ([K*K][256] per scale)
// cka[j]     = sum_{c<128} wa[c,j] * bk[c]
// ---------------------------------------------------------------------------
template<int K>
__device__ __forceinline__ void wka_body(
    const float* __restrict__ wa, const float* __restrict__ wk,
    const float* __restrict__ bk, float* __restrict__ WKA,
    float* __restrict__ cka, int ji, int tid)
{
  if (ji >= K * K) return;
  const int j = ji / K, i = ji - j * K;
  float acc = 0.f;
  for (int c = 0; c < 128; ++c)
    acc += wa[c * K + j] * wk[((size_t)(c * 256 + tid)) * K + i];
  WKA[(size_t)ji * 256 + tid] = acc;
  if (i == 0 && tid == 0) {
    float s = 0.f;
    for (int c = 0; c < 128; ++c) s += wa[c * K + j] * bk[c];
    cka[j] = s;
  }
}

__global__ __launch_bounds__(256) void wka_kernel(
    const float* wa0, const float* wk0, const float* bk0,
    const float* wa1, const float* wk1, const float* bk1,
    const float* wa2, const float* wk2, const float* bk2,
    float* WKA, float* cka)
{
  const int s = blockIdx.y, ji = blockIdx.x, tid = threadIdx.x;
  float* wkap = WKA + (size_t)s * 121 * 256;
  float* ckap = cka + s * 11;
  if (s == 0)      wka_body<3>(wa0, wk0, bk0, wkap, ckap, ji, tid);
  else if (s == 1) wka_body<7>(wa1, wk1, bk1, wkap, ckap, ji, tid);
  else             wka_body<11>(wa2, wk2, bk2, wkap, ckap, ji, tid);
}

// ---------------------------------------------------------------------------
// Weight folding stage 2 (padded layout for b128 LDS reads downstream):
// WXA[c][i][jp] (jp = K padded to mult-of-4) = sum_{c'} WKA[j,i,c'] * wp[c',c]
// bpA[j][i]                                  = sum_{c'} WKA[j,i,c'] * bp[c']
// ---------------------------------------------------------------------------
template<int K>
__device__ __forceinline__ void wxa_body(
    const float* __restrict__ WKA, const float* __restrict__ wp,
    const float* __restrict__ bp, float* __restrict__ WXA,
    float* __restrict__ bpA, int ji, int tid)
{
  if (ji >= K * K) return;
  constexpr int KP = (K + 3) & ~3;
  const int j = ji / K, i = ji - j * K;
  const float* row = &WKA[(size_t)ji * 256];
  float acc = 0.f;
  for (int c = 0; c < 256; ++c) acc += row[c] * wp[(size_t)c * 512 + tid];
  WXA[(size_t)tid * K * KP + i * KP + j] = acc;
  if (tid == 0) {
    float s = 0.f;
    for (int c = 0; c < 256; ++c) s += row[c] * bp[c];
    bpA[j * 11 + i] = s;
  }
}

__global__ __launch_bounds__(512) void wxa_kernel(
    const float* WKA,
    const float* wp0, const float* bp0,
    const float* wp1, const float* bp1,
    const float* wp2, const float* bp2,
    float* WXA, float* bpA)
{
  const int s = blockIdx.y, ji = blockIdx.x, tid = threadIdx.x;
  const float* wkap = WKA + (size_t)s * 121 * 256;
  float* bpap = bpA + s * 121;
  if (s == 0)      wxa_body<3> (wkap, wp0, bp0, WXA,         bpap, ji, tid);
  else if (s == 1) wxa_body<7> (wkap, wp1, bp1, WXA + 6144,  bpap, ji, tid);
  else             wxa_body<11>(wkap, wp2, bp2, WXA + 34816, bpap, ji, tid);
}

// ---------------------------------------------------------------------------
// Banded conv on x, v2: 16 channels/block, weights staged in LDS (broadcast),
// 4 t per thread, 4-way intra-block channel split + LDS reduce.
// rpart[s][n][cc][j][t] = sum_{c in 16-chunk, i} WXA[c,i,j] * xpad[n,c,t+i-A]
// Block: 192 threads = c_sub(4) x tq(48); thread owns 4 channels x 4 t.
// ---------------------------------------------------------------------------
template<int A>
__device__ __forceinline__ void rcomp_body(
    const float* __restrict__ x, const float* __restrict__ WXAs,
    float* __restrict__ rps, float* Xs, float* Wl, float* Pl,
    int cc, int n, int tid)
{
  constexpr int K   = 2 * A + 1;
  constexpr int KP  = (K + 3) & ~3;
  constexpr int NF4 = KP / 4;
  constexpr int WH  = 192 + 2 * A;   // staged width
  constexpr int WP  = 208;           // padded row stride (16B-mult, fits reads)
  const int c_sub = tid / 48;
  const int tq    = tid - c_sub * 48;
  const int c0    = cc * 16;

  // stage x rows (zero halo)
  for (int idx = tid; idx < 16 * WH; idx += 192) {
    int c = idx / WH, p = idx - c * WH;
    int tau = p - A;
    Xs[c * WP + p] = (tau >= 0 && tau < 192)
        ? x[((size_t)n * 512 + c0 + c) * 192 + tau] : 0.f;
  }
  // stage weights (already padded layout in global)
  {
    const float4* wg = reinterpret_cast<const float4*>(WXAs + (size_t)c0 * K * KP);
    float4* wl = reinterpret_cast<float4*>(Wl);
    for (int idx = tid; idx < 16 * K * KP / 4; idx += 192) wl[idx] = wg[idx];
  }
  __syncthreads();

  float4 acc[K];
#pragma unroll
  for (int j = 0; j < K; ++j) acc[j] = make_float4(0.f, 0.f, 0.f, 0.f);

#pragma unroll
  for (int c = 0; c < 4; ++c) {
    const int ch = c_sub * 4 + c;
    float win[16];
    const float* xrow = &Xs[ch * WP + tq * 4];
#pragma unroll
    for (int q = 0; q < 4; ++q)
      *reinterpret_cast<float4*>(&win[q * 4]) =
          *reinterpret_cast<const float4*>(&xrow[q * 4]);
    const float* wrow = &Wl[ch * K * KP];
#pragma unroll
    for (int i = 0; i < K; ++i) {
#pragma unroll
      for (int f = 0; f < NF4; ++f) {
        float4 w = *reinterpret_cast<const float4*>(&wrow[i * KP + f * 4]);
#pragma unroll
        for (int jj = 0; jj < 4; ++jj) {
          constexpr int dummy = 0; (void)dummy;
          int j = f * 4 + jj;
          if (j < K) {
            float wv = jj == 0 ? w.x : jj == 1 ? w.y : jj == 2 ? w.z : w.w;
            acc[f * 4 + jj].x += wv * win[i + 0];
            acc[f * 4 + jj].y += wv * win[i + 1];
            acc[f * 4 + jj].z += wv * win[i + 2];
            acc[f * 4 + jj].w += wv * win[i + 3];
          }
        }
      }
    }
  }

  // intra-block reduce over c_sub
  if (c_sub > 0) {
#pragma unroll
    for (int j = 0; j < K; ++j)
      *reinterpret_cast<float4*>(&Pl[((c_sub - 1) * K + j) * 192 + tq * 4]) = acc[j];
  }
  __syncthreads();
  if (c_sub == 0) {
#pragma unroll
    for (int j = 0; j < K; ++j) {
      float4 r = acc[j];
      float4 p0 = *reinterpret_cast<const float4*>(&Pl[(0 * K + j) * 192 + tq * 4]);
      float4 p1 = *reinterpret_cast<const float4*>(&Pl[(1 * K + j) * 192 + tq * 4]);
      float4 p2 = *reinterpret_cast<const float4*>(&Pl[(2 * K + j) * 192 + tq * 4]);
      r.x += p0.x + p1.x + p2.x; r.y += p0.y + p1.y + p2.y;
      r.z += p0.z + p1.z + p2.z; r.w += p0.w + p1.w + p2.w;
      *reinterpret_cast<float4*>(
          &rps[(((size_t)n * 32 + cc) * K + j) * 192 + tq * 4]) = r;
    }
  }
}

__global__ __launch_bounds__(192) void rcomp_kernel(
    const float* __restrict__ x, const float* __restrict__ WXA,
    float* __restrict__ rpart)
{
  __shared__ float lds[11776];     // Xs 16*208 | W <=2112 | P 3*11*192
  float* Xs = lds;
  float* Wl = lds + 3328;
  float* Pl = lds + 5440;
  const int cc = blockIdx.x, n = blockIdx.y, s = blockIdx.z;
  const int tid = threadIdx.x;
  if (s == 0)      rcomp_body<1>(x, WXA,         rpart,          Xs, Wl, Pl, cc, n, tid);
  else if (s == 1) rcomp_body<3>(x, WXA + 6144,  rpart + 147456, Xs, Wl, Pl, cc, n, tid);
  else             rcomp_body<5>(x, WXA + 34816, rpart + 491520, Xs, Wl, Pl, cc, n, tid);
}

// ---------------------------------------------------------------------------
// rbuf[s][n][j][t] = sum_cc rpart + cka[j] + sum_i 1[0<=t+i-A<T]*bpA[j,i]
// grid (8 n, 21 sj): one (s,j) per block.
// ---------------------------------------------------------------------------
__global__ __launch_bounds__(192) void rreduce_kernel(
    const float* __restrict__ rpart, const float* __restrict__ cka,
    const float* __restrict__ bpA, float* __restrict__ rbuf)
{
  const int n = blockIdx.x, sj = blockIdx.y, t = threadIdx.x;
  const int s = sj < 3 ? 0 : sj < 10 ? 1 : 2;
  const int j = sj < 3 ? sj : sj < 10 ? sj - 3 : sj - 10;
  const int A = (s == 0) ? 1 : (s == 1) ? 3 : 5;
  const int K = 2 * A + 1;
  const int roff = (s == 0) ? 0 : (s == 1) ? 147456 : 491520;
  const float* rp = rpart + roff;
  float acc = cka[s * 11 + j];
#pragma unroll 8
  for (int cc = 0; cc < 32; ++cc)
    acc += rp[(((size_t)n * 32 + cc) * K + j) * 192 + t];
  for (int i = 0; i < K; ++i) {
    int tau = t + i - A;
    if (tau >= 0 && tau < 192) acc += bpA[s * 121 + j * 11 + i];
  }
  rbuf[((size_t)(s * 8 + n) * 11 + j) * 192 + t] = acc;
}

// ---------------------------------------------------------------------------
// Per (n,u) column: banded logits, softmax over t (3 scales), summed.
// Writes At[n][u][t] (for final GEMM) and Aout[n][t][u] (module output).
// ---------------------------------------------------------------------------
template<int A>
__device__ __forceinline__ float gather_val(const float* __restrict__ rs,
                                            int t, int u)
{
  constexpr int K = 2 * A + 1;
  float val = 0.f;
#pragma unroll
  for (int j = 0; j < K; ++j) {
    int tp = t + j - A;
    int d = tp - u;
    if (tp >= 0 && tp < 192 && d <= A && d >= -A) val += rs[j * 192 + tp];
  }
  return val;
}

__global__ __launch_bounds__(192) void abuild_kernel(
    const float* __restrict__ rbuf,
    const float* __restrict__ ba0, const float* __restrict__ ba1,
    const float* __restrict__ ba2, float* __restrict__ At,
    float* __restrict__ Aout)
{
  const int u = blockIdx.x, n = blockIdx.y;
  const int t = threadIdx.x;
  const int lane = t & 63, wid = t >> 6;
  __shared__ float wm[3][3], wsm[3][3];

  float v0 = ba0[0] + gather_val<1>(rbuf + (size_t)(0 * 8 + n) * 11 * 192, t, u);
  float v1 = ba1[0] + gather_val<3>(rbuf + (size_t)(1 * 8 + n) * 11 * 192, t, u);
  float v2 = ba2[0] + gather_val<5>(rbuf + (size_t)(2 * 8 + n) * 11 * 192, t, u);

  float m0 = v0, m1 = v1, m2 = v2;
#pragma unroll
  for (int off = 32; off > 0; off >>= 1) {
    m0 = fmaxf(m0, __shfl_xor(m0, off));
    m1 = fmaxf(m1, __shfl_xor(m1, off));
    m2 = fmaxf(m2, __shfl_xor(m2, off));
  }
  if (lane == 0) { wm[wid][0] = m0; wm[wid][1] = m1; wm[wid][2] = m2; }
  __syncthreads();
  m0 = fmaxf(fmaxf(wm[0][0], wm[1][0]), wm[2][0]);
  m1 = fmaxf(fmaxf(wm[0][1], wm[1][1]), wm[2][1]);
  m2 = fmaxf(fmaxf(wm[0][2], wm[1][2]), wm[2][2]);

  float e0 = __expf(v0 - m0), e1 = __expf(v1 - m1), e2 = __expf(v2 - m2);
  float s0 = e0, s1 = e1, s2 = e2;
#pragma unroll
  for (int off = 32; off > 0; off >>= 1) {
    s0 += __shfl_xor(s0, off);
    s1 += __shfl_xor(s1, off);
    s2 += __shfl_xor(s2, off);
  }
  if (lane == 0) { wsm[wid][0] = s0; wsm[wid][1] = s1; wsm[wid][2] = s2; }
  __syncthreads();
  s0 = wsm[0][0] + wsm[1][0] + wsm[2][0];
  s1 = wsm[0][1] + wsm[1][1] + wsm[2][1];
  s2 = wsm[0][2] + wsm[1][2] + wsm[2][2];

  float v = e0 / s0 + e1 / s1 + e2 / s2;
  At[((size_t)n * 192 + u) * 192 + t] = v;
  Aout[((size_t)n * 192 + t) * 192 + u] = v;   // scattered transpose write
}

// ---------------------------------------------------------------------------
// Grouped conv (groups=32, K=3) + ReLU. hall ch0..255 (h1) -> ch256..511 (h2).
// ---------------------------------------------------------------------------
__global__ void gconv_kernel(const float* hin, const float* __restrict__ w2,
                             const float* __restrict__ b2, float* hout)
{
  const int t  = threadIdx.x + blockIdx.x * 64;
  const int oc = threadIdx.y + blockIdx.y * 4;
  const int n  = blockIdx.z;
  const int g  = oc >> 3;
  float acc = b2[oc];
  for (int i = 0; i < 8; ++i) {
    const float* hrow = &hin[((size_t)n * 512 + g * 8 + i) * 192];
#pragma unroll
    for (int j = 0; j < 3; ++j) {
      int tt = t + j - 1;
      float hv = (tt >= 0 && tt < 192) ? hrow[tt] : 0.f;
      acc += w2[((size_t)oc * 8 + i) * 3 + j] * hv;
    }
  }
  hout[((size_t)n * 512 + 256 + oc) * 192 + t] = fmaxf(acc, 0.f);
}

// ---------------------------------------------------------------------------
extern "C" void kernel_launch(void* const* d_in, const int* in_sizes, int n_in,
                              void* d_out, int out_size, void* d_ws, size_t ws_size,
                              hipStream_t stream)
{
  const float* x   = (const float*)d_in[0];
  const float* wp0 = (const float*)d_in[1];
  const float* bp0 = (const float*)d_in[2];
  const float* wk0 = (const float*)d_in[3];
  const float* bk0 = (const float*)d_in[4];
  const float* wa0 = (const float*)d_in[5];
  const float* ba0 = (const float*)d_in[6];
  const float* wp1 = (const float*)d_in[7];
  const float* bp1 = (const float*)d_in[8];
  const float* wk1 = (const float*)d_in[9];
  const float* bk1 = (const float*)d_in[10];
  const float* wa1 = (const float*)d_in[11];
  const float* ba1 = (const float*)d_in[12];
  const float* wp2 = (const float*)d_in[13];
  const float* bp2 = (const float*)d_in[14];
  const float* wk2 = (const float*)d_in[15];
  const float* bk2 = (const float*)d_in[16];
  const float* wa2 = (const float*)d_in[17];
  const float* ba2 = (const float*)d_in[18];
  const float* w1  = (const float*)d_in[19];
  const float* b1  = (const float*)d_in[20];
  const float* w2  = (const float*)d_in[21];
  const float* b2  = (const float*)d_in[22];
  const float* w3  = (const float*)d_in[23];
  const float* b3  = (const float*)d_in[24];

  float* ws    = (float*)d_ws;
  float* hall  = ws;                          // [8][512][192]      =   786,432
  float* At    = hall  + 786432;              // [8][192][192]      =   294,912
  float* xs    = At    + 294912;              // [8][256][192]      =   393,216
  float* rpart = xs    + 393216;              // [8][32][3+7+11][192] = 1,032,192
  float* rbuf  = rpart + 1032192;             // [3][8][11][192]    =    50,688
  float* WKA   = rbuf  + 50688;               // [3][121][256]      =    92,928
  float* WXA   = WKA   + 92928;               // [512]*(12+56+132)  =   102,400
  float* bpA   = WXA   + 102400;              // [3][121]           =       384
  float* cka   = bpA   + 384;                 // [3][11]            =        48
  float* out0  = (float*)d_out;               // [8][256][192]
  float* Aout  = out0 + 8 * 256 * 192;        // [8][192][192]

  // --- weight folding (per call) ---
  wka_kernel<<<dim3(121, 3), 256, 0, stream>>>(
      wa0, wk0, bk0, wa1, wk1, bk1, wa2, wk2, bk2, WKA, cka);
  wxa_kernel<<<dim3(121, 3), 512, 0, stream>>>(
      WKA, wp0, bp0, wp1, bp1, wp2, bp2, WXA, bpA);

  // --- main path h1 = w1 @ x ---
  gemm1x1_kernel<512><<<dim3(3, 4, 8), 256, 0, stream>>>(
      w1, b1, x, hall, 512, 512, 0);

  // --- banded r directly from x ---
  rcomp_kernel<<<dim3(32, 8, 3), 192, 0, stream>>>(x, WXA, rpart);
  rreduce_kernel<<<dim3(8, 21), 192, 0, stream>>>(rpart, cka, bpA, rbuf);

  // --- A build (writes both At and Aout) ---
  abuild_kernel<<<dim3(192, 8), 192, 0, stream>>>(rbuf, ba0, ba1, ba2, At, Aout);

  // --- main path tail ---
  gconv_kernel<<<dim3(3, 64, 8), dim3(64, 4), 0, stream>>>(hall, w2, b2, hall);
  gemm1x1_kernel<256><<<dim3(3, 4, 8), 256, 0, stream>>>(
      w3, b3, hall + 256 * 192, xs, 512, 256, 0);
  gemm1x1_kernel<192><<<dim3(3, 4, 8), 256, 0, stream>>>(
      xs, nullptr, Aout, out0, 192, 256, 256 * 192);
}

// Round 4
// 90.238 us; speedup vs baseline: 2.1868x; 1.3715x over previous
//
#include <hip/hip_runtime.h>

#define T_LEN 192

// ===========================================================================
// Device bodies (fused into 5 kernels by block-range dispatch; all 256 thr)
// ===========================================================================

// ---- tiled GEMM body: Y[n,o,t] = sum_c W[o,c]*X[c,t] + B[o] ---------------
// TRANSX=false: X[c,t] = Xg[(n*cstr + c)*192 + t]
// TRANSX=true : X[c,u] = Xg[(n*192 + u)*192 + c]   (At layout, transposed)
template<bool TRANSX>
__device__ __forceinline__ void gemm_body(
    float* smem,
    const float* __restrict__ W, const float* __restrict__ B,
    const float* __restrict__ X, float* __restrict__ Y,
    int cin, int cstr, int ostr, int wnstr,
    int t0, int o0, int n, int tid)
{
  float (*Ws)[68] = (float(*)[68])smem;            // [c][o]
  float (*Xs)[68] = (float(*)[68])(smem + 64 * 68); // [c][t]
  const int to = tid >> 4, tt = tid & 15;
  float acc[4][4] = {};

  for (int c0 = 0; c0 < cin; c0 += 64) {
    __syncthreads();
#pragma unroll
    for (int l = 0; l < 4; ++l) {
      int idx = l * 256 + tid;
      int rr = idx >> 4, c4 = idx & 15;
      float4 wv = *reinterpret_cast<const float4*>(
          &W[(size_t)n * wnstr + (size_t)(o0 + rr) * cin + c0 + c4 * 4]);
      Ws[c4 * 4 + 0][rr] = wv.x; Ws[c4 * 4 + 1][rr] = wv.y;
      Ws[c4 * 4 + 2][rr] = wv.z; Ws[c4 * 4 + 3][rr] = wv.w;
      if (!TRANSX) {
        float4 xv = *reinterpret_cast<const float4*>(
            &X[((size_t)n * cstr + c0 + rr) * T_LEN + t0 + c4 * 4]);
        *reinterpret_cast<float4*>(&Xs[rr][c4 * 4]) = xv;
      } else {
        float4 xv = *reinterpret_cast<const float4*>(
            &X[((size_t)n * 192 + t0 + rr) * 192 + c0 + c4 * 4]);
        Xs[c4 * 4 + 0][rr] = xv.x; Xs[c4 * 4 + 1][rr] = xv.y;
        Xs[c4 * 4 + 2][rr] = xv.z; Xs[c4 * 4 + 3][rr] = xv.w;
      }
    }
    __syncthreads();
#pragma unroll
    for (int kk = 0; kk < 64; ++kk) {
      float4 a = *reinterpret_cast<const float4*>(&Ws[kk][to * 4]);
      float4 b = *reinterpret_cast<const float4*>(&Xs[kk][tt * 4]);
      acc[0][0] += a.x * b.x; acc[0][1] += a.x * b.y; acc[0][2] += a.x * b.z; acc[0][3] += a.x * b.w;
      acc[1][0] += a.y * b.x; acc[1][1] += a.y * b.y; acc[1][2] += a.y * b.z; acc[1][3] += a.y * b.w;
      acc[2][0] += a.z * b.x; acc[2][1] += a.z * b.y; acc[2][2] += a.z * b.z; acc[2][3] += a.z * b.w;
      acc[3][0] += a.w * b.x; acc[3][1] += a.w * b.y; acc[3][2] += a.w * b.z; acc[3][3] += a.w * b.w;
    }
  }
#pragma unroll
  for (int i = 0; i < 4; ++i) {
    float bi = B ? B[o0 + to * 4 + i] : 0.f;
    float4 v = make_float4(acc[i][0] + bi, acc[i][1] + bi, acc[i][2] + bi, acc[i][3] + bi);
    *reinterpret_cast<float4*>(
        &Y[((size_t)n * ostr + o0 + to * 4 + i) * T_LEN + t0 + tt * 4]) = v;
  }
}

// ---- banded conv on x: rpart[n,cc,j,t] = sum_{16ch,i} WXA[c,i,j]*xpad -----
// 4 waves x 48 t; lane = csub(4) x tpos(16); 3 t per lane; shfl csub-reduce.
template<int A>
__device__ __forceinline__ void rcomp_body(
    float* smem, const float* __restrict__ x, const float* __restrict__ WXAs,
    float* __restrict__ rps, int cc, int n, int tid)
{
  constexpr int K  = 2 * A + 1;
  constexpr int KP = (K + 3) & ~3;
  constexpr int WH = 192 + 2 * A;
  constexpr int WS = 204;
  float* Xs = smem;               // 16 x 204
  float* Wl = smem + 16 * WS;     // 16 x K x KP
  const int c0 = cc * 16;

  for (int idx = tid; idx < 16 * WH; idx += 256) {
    int c = idx / WH, p = idx - c * WH;
    int tau = p - A;
    Xs[c * WS + p] = (tau >= 0 && tau < 192)
        ? x[((size_t)n * 512 + c0 + c) * 192 + tau] : 0.f;
  }
  {
    const float4* wg = reinterpret_cast<const float4*>(WXAs + (size_t)c0 * K * KP);
    float4* wl = reinterpret_cast<float4*>(Wl);
    for (int idx = tid; idx < 16 * K * KP / 4; idx += 256) wl[idx] = wg[idx];
  }
  __syncthreads();

  const int w = tid >> 6, lane = tid & 63;
  const int csub = lane >> 4, tpos = lane & 15;
  const int tb = w * 48 + tpos * 3;

  float acc[K][3];
#pragma unroll
  for (int j = 0; j < K; ++j) { acc[j][0] = 0.f; acc[j][1] = 0.f; acc[j][2] = 0.f; }

#pragma unroll
  for (int c = 0; c < 4; ++c) {
    const int ch = csub * 4 + c;
    float win[K + 2];
#pragma unroll
    for (int p = 0; p < K + 2; ++p) win[p] = Xs[ch * WS + tb + p];
    const float* wr = &Wl[ch * K * KP];
#pragma unroll
    for (int i = 0; i < K; ++i) {
#pragma unroll
      for (int j = 0; j < K; ++j) {
        float wv = wr[i * KP + j];
        acc[j][0] += wv * win[i + 0];
        acc[j][1] += wv * win[i + 1];
        acc[j][2] += wv * win[i + 2];
      }
    }
  }
#pragma unroll
  for (int j = 0; j < K; ++j) {
#pragma unroll
    for (int q = 0; q < 3; ++q) {
      float v = acc[j][q];
      v += __shfl_xor(v, 16);
      v += __shfl_xor(v, 32);
      acc[j][q] = v;
    }
  }
  if (csub == 0) {
#pragma unroll
    for (int j = 0; j < K; ++j) {
      float* dst = &rps[(((size_t)n * 32 + cc) * K + j) * 192 + tb];
      dst[0] = acc[j][0]; dst[1] = acc[j][1]; dst[2] = acc[j][2];
    }
  }
}

// ---- rreduce: rbuf[s,n,j,t] = sum_cc rpart + cka + boundary bp term -------
__device__ __forceinline__ void rreduce_body(
    const float* __restrict__ rpart, const float* __restrict__ cka,
    const float* __restrict__ bpA, float* __restrict__ rbuf,
    int n, int sj, int t)
{
  if (t >= 192) return;
  const int s = sj < 3 ? 0 : sj < 10 ? 1 : 2;
  const int j = sj < 3 ? sj : sj < 10 ? sj - 3 : sj - 10;
  const int A = (s == 0) ? 1 : (s == 1) ? 3 : 5;
  const int K = 2 * A + 1;
  const int roff = (s == 0) ? 0 : (s == 1) ? 147456 : 491520;
  const float* rp = rpart + roff;
  float acc = cka[s * 11 + j];
#pragma unroll 8
  for (int cc = 0; cc < 32; ++cc)
    acc += rp[(((size_t)n * 32 + cc) * K + j) * 192 + t];
  for (int i = 0; i < K; ++i) {
    int tau = t + i - A;
    if (tau >= 0 && tau < 192) acc += bpA[s * 121 + j * 11 + i];
  }
  rbuf[((size_t)(s * 8 + n) * 11 + j) * 192 + t] = acc;
}

// ---- abuild: 1 wave = 1 softmax column u; 64 lanes x 3 t; shfl-only -------
template<int A>
__device__ __forceinline__ float gather_val(const float* __restrict__ rs,
                                            int t, int u)
{
  constexpr int K = 2 * A + 1;
  float val = 0.f;
#pragma unroll
  for (int j = 0; j < K; ++j) {
    int tp = t + j - A;
    int d = tp - u;
    if (tp >= 0 && tp < 192 && d <= A && d >= -A) val += rs[j * 192 + tp];
  }
  return val;
}

__device__ __forceinline__ void abuild_body(
    const float* __restrict__ rbuf,
    const float* __restrict__ ba0, const float* __restrict__ ba1,
    const float* __restrict__ ba2, float* __restrict__ At,
    int ublk, int n, int tid)
{
  const int w = tid >> 6, lane = tid & 63;
  const int u = ublk * 4 + w;
  const int t0 = lane * 3;
  const float* r0 = rbuf + (size_t)(0 * 8 + n) * 11 * 192;
  const float* r1 = rbuf + (size_t)(1 * 8 + n) * 11 * 192;
  const float* r2 = rbuf + (size_t)(2 * 8 + n) * 11 * 192;
  float v0[3], v1[3], v2[3];
  const float b0 = ba0[0], b1 = ba1[0], b2 = ba2[0];
#pragma unroll
  for (int q = 0; q < 3; ++q) {
    v0[q] = b0 + gather_val<1>(r0, t0 + q, u);
    v1[q] = b1 + gather_val<3>(r1, t0 + q, u);
    v2[q] = b2 + gather_val<5>(r2, t0 + q, u);
  }
  float m0 = fmaxf(fmaxf(v0[0], v0[1]), v0[2]);
  float m1 = fmaxf(fmaxf(v1[0], v1[1]), v1[2]);
  float m2 = fmaxf(fmaxf(v2[0], v2[1]), v2[2]);
#pragma unroll
  for (int off = 32; off > 0; off >>= 1) {
    m0 = fmaxf(m0, __shfl_xor(m0, off));
    m1 = fmaxf(m1, __shfl_xor(m1, off));
    m2 = fmaxf(m2, __shfl_xor(m2, off));
  }
  float e0[3], e1[3], e2[3];
#pragma unroll
  for (int q = 0; q < 3; ++q) {
    e0[q] = __expf(v0[q] - m0);
    e1[q] = __expf(v1[q] - m1);
    e2[q] = __expf(v2[q] - m2);
  }
  float s0 = e0[0] + e0[1] + e0[2];
  float s1 = e1[0] + e1[1] + e1[2];
  float s2 = e2[0] + e2[1] + e2[2];
#pragma unroll
  for (int off = 32; off > 0; off >>= 1) {
    s0 += __shfl_xor(s0, off);
    s1 += __shfl_xor(s1, off);
    s2 += __shfl_xor(s2, off);
  }
  const float i0 = 1.f / s0, i1 = 1.f / s1, i2 = 1.f / s2;
  float* dst = &At[((size_t)n * 192 + u) * 192 + t0];
#pragma unroll
  for (int q = 0; q < 3; ++q)
    dst[q] = e0[q] * i0 + e1[q] * i1 + e2[q] * i2;
}

// ---- grouped conv (groups=32, K=3) + ReLU ---------------------------------
__device__ __forceinline__ void gconv_body(
    const float* __restrict__ hin, const float* __restrict__ w2,
    const float* __restrict__ b2, float* __restrict__ hout,
    int bx, int by, int n, int tid)
{
  const int t  = (tid & 63) + bx * 64;
  const int oc = (tid >> 6) + by * 4;
  const int g  = oc >> 3;
  float acc = b2[oc];
  for (int i = 0; i < 8; ++i) {
    const float* hrow = &hin[((size_t)n * 512 + g * 8 + i) * 192];
#pragma unroll
    for (int j = 0; j < 3; ++j) {
      int tt = t + j - 1;
      float hv = (tt >= 0 && tt < 192) ? hrow[tt] : 0.f;
      acc += w2[((size_t)oc * 8 + i) * 3 + j] * hv;
    }
  }
  hout[((size_t)n * 512 + 256 + oc) * 192 + t] = fmaxf(acc, 0.f);
}

// ---- At[n][u][t] -> Aout[n][t][u] ------------------------------------------
__device__ __forceinline__ void transpose_body(
    float* smem, const float* __restrict__ At, float* __restrict__ Aout,
    int bx, int by, int n, int tid)
{
  float (*tile)[33] = (float(*)[33])smem;
  const int xx = tid & 31, y = tid >> 5;
  for (int yy = y; yy < 32; yy += 8)
    tile[yy][xx] = At[((size_t)n * 192 + by * 32 + yy) * 192 + bx * 32 + xx];
  __syncthreads();
  for (int yy = y; yy < 32; yy += 8)
    Aout[((size_t)n * 192 + bx * 32 + yy) * 192 + by * 32 + xx] = tile[xx][yy];
}

// ===========================================================================
// K1: fused weight folding.  block (s,ji):
//   row[c'] = sum_c wa[c,j]*wk[c,c',i]        (LDS handoff)
//   WXA[cin,i,jp] = sum_c' row[c']*wp[c',cin];  bpA, cka side terms.
// ===========================================================================
__global__ __launch_bounds__(256) void foldw_kernel(
    const float* __restrict__ wa0, const float* __restrict__ wk0,
    const float* __restrict__ bk0, const float* __restrict__ wp0,
    const float* __restrict__ bp0,
    const float* __restrict__ wa1, const float* __restrict__ wk1,
    const float* __restrict__ bk1, const float* __restrict__ wp1,
    const float* __restrict__ bp1,
    const float* __restrict__ wa2, const float* __restrict__ wk2,
    const float* __restrict__ bk2, const float* __restrict__ wp2,
    const float* __restrict__ bp2,
    float* __restrict__ WXA, float* __restrict__ bpA, float* __restrict__ cka)
{
  __shared__ float wa_lds[128];
  __shared__ float rowbuf[256];
  const int bid = blockIdx.x, tid = threadIdx.x;
  int s, ji, K;
  const float *wa, *wk, *bk, *wp, *bp;
  float* wxas;
  if (bid < 9)       { s = 0; ji = bid;      K = 3;  wa = wa0; wk = wk0; bk = bk0; wp = wp0; bp = bp0; wxas = WXA; }
  else if (bid < 58) { s = 1; ji = bid - 9;  K = 7;  wa = wa1; wk = wk1; bk = bk1; wp = wp1; bp = bp1; wxas = WXA + 6144; }
  else               { s = 2; ji = bid - 58; K = 11; wa = wa2; wk = wk2; bk = bk2; wp = wp2; bp = bp2; wxas = WXA + 34816; }
  const int KP = (K + 3) & ~3;
  const int j = ji / K, i = ji - j * K;

  if (tid < 128) wa_lds[tid] = wa[tid * K + j];
  __syncthreads();

  float acc = 0.f;
  for (int c = 0; c < 128; ++c)
    acc += wa_lds[c] * wk[((size_t)(c * 256) + tid) * K + i];
  rowbuf[tid] = acc;
  __syncthreads();

  for (int rep = 0; rep < 2; ++rep) {
    const int cin = tid + rep * 256;
    float a2 = 0.f;
    for (int c = 0; c < 256; ++c) a2 += rowbuf[c] * wp[(size_t)c * 512 + cin];
    wxas[(size_t)cin * K * KP + i * KP + j] = a2;
  }
  if (tid == 0) {
    float sb = 0.f;
    for (int c = 0; c < 256; ++c) sb += rowbuf[c] * bp[c];
    bpA[s * 121 + j * 11 + i] = sb;
  }
  if (i == 0 && tid == 64) {
    float sc = 0.f;
    for (int c = 0; c < 128; ++c) sc += wa_lds[c] * bk[c];
    cka[s * 11 + j] = sc;
  }
}

// ===========================================================================
// K2: gemm512 (h1 = w1@x, 96 blocks)  ||  rcomp (768 blocks)
// ===========================================================================
__global__ __launch_bounds__(256) void k2_kernel(
    const float* __restrict__ x, const float* __restrict__ w1,
    const float* __restrict__ b1, const float* __restrict__ WXA,
    float* __restrict__ hall, float* __restrict__ rpart)
{
  __shared__ __align__(16) float smem[8704];
  const int bid = blockIdx.x, tid = threadIdx.x;
  if (bid < 96) {
    const int tx = bid % 3, oy = (bid / 3) % 4, n = bid / 12;
    gemm_body<false>(smem, w1, b1, x, hall, 512, 512, 512, 0,
                     tx * 64, oy * 64, n, tid);
  } else {
    const int rid = bid - 96;
    const int cc = rid % 32, n = (rid / 32) % 8, s = rid / 256;
    if (s == 0)      rcomp_body<1>(smem, x, WXA,         rpart,          cc, n, tid);
    else if (s == 1) rcomp_body<3>(smem, x, WXA + 6144,  rpart + 147456, cc, n, tid);
    else             rcomp_body<5>(smem, x, WXA + 34816, rpart + 491520, cc, n, tid);
  }
}

// ===========================================================================
// K3: rreduce (168 blocks)  ||  gconv (1536 blocks)
// ===========================================================================
__global__ __launch_bounds__(256) void k3_kernel(
    const float* __restrict__ rpart, const float* __restrict__ cka,
    const float* __restrict__ bpA, float* __restrict__ rbuf,
    const float* __restrict__ w2, const float* __restrict__ b2,
    float* __restrict__ hall)
{
  const int bid = blockIdx.x, tid = threadIdx.x;
  if (bid < 168) {
    rreduce_body(rpart, cka, bpA, rbuf, bid % 8, bid / 8, tid);
  } else {
    const int gid = bid - 168;
    gconv_body(hall, w2, b2, hall, gid % 3, (gid / 3) % 64, gid / 192, tid);
  }
}

// ===========================================================================
// K4: abuild (384 blocks)  ||  gemm w3 (xs = w3@h2, 96 blocks)
// ===========================================================================
__global__ __launch_bounds__(256) void k4_kernel(
    const float* __restrict__ rbuf,
    const float* __restrict__ ba0, const float* __restrict__ ba1,
    const float* __restrict__ ba2, float* __restrict__ At,
    const float* __restrict__ hall, const float* __restrict__ w3,
    const float* __restrict__ b3, float* __restrict__ xs)
{
  __shared__ __align__(16) float smem[8704];
  const int bid = blockIdx.x, tid = threadIdx.x;
  if (bid < 384) {
    abuild_body(rbuf, ba0, ba1, ba2, At, bid % 48, bid / 48, tid);
  } else {
    const int gid = bid - 384;
    const int tx = gid % 3, oy = (gid / 3) % 4, n = gid / 12;
    gemm_body<false>(smem, w3, b3, hall + 256 * 192, xs, 256, 512, 256, 0,
                     tx * 64, oy * 64, n, tid);
  }
}

// ===========================================================================
// K5: out0 = xs@A (96 blocks, At read transposed)  ||  transpose (288 blocks)
// ===========================================================================
__global__ __launch_bounds__(256) void k5_kernel(
    const float* __restrict__ xs, const float* __restrict__ At,
    float* __restrict__ out0, float* __restrict__ Aout)
{
  __shared__ __align__(16) float smem[8704];
  const int bid = blockIdx.x, tid = threadIdx.x;
  if (bid < 96) {
    const int tx = bid % 3, oy = (bid / 3) % 4, n = bid / 12;
    gemm_body<true>(smem, xs, nullptr, At, out0, 192, 0, 256, 256 * 192,
                    tx * 64, oy * 64, n, tid);
  } else {
    const int gid = bid - 96;
    transpose_body(smem, At, Aout, gid % 6, (gid / 6) % 6, gid / 36, tid);
  }
}

// ===========================================================================
extern "C" void kernel_launch(void* const* d_in, const int* in_sizes, int n_in,
                              void* d_out, int out_size, void* d_ws, size_t ws_size,
                              hipStream_t stream)
{
  const float* x   = (const float*)d_in[0];
  const float* wp0 = (const float*)d_in[1];
  const float* bp0 = (const float*)d_in[2];
  const float* wk0 = (const float*)d_in[3];
  const float* bk0 = (const float*)d_in[4];
  const float* wa0 = (const float*)d_in[5];
  const float* ba0 = (const float*)d_in[6];
  const float* wp1 = (const float*)d_in[7];
  const float* bp1 = (const float*)d_in[8];
  const float* wk1 = (const float*)d_in[9];
  const float* bk1 = (const float*)d_in[10];
  const float* wa1 = (const float*)d_in[11];
  const float* ba1 = (const float*)d_in[12];
  const float* wp2 = (const float*)d_in[13];
  const float* bp2 = (const float*)d_in[14];
  const float* wk2 = (const float*)d_in[15];
  const float* bk2 = (const float*)d_in[16];
  const float* wa2 = (const float*)d_in[17];
  const float* ba2 = (const float*)d_in[18];
  const float* w1  = (const float*)d_in[19];
  const float* b1  = (const float*)d_in[20];
  const float* w2  = (const float*)d_in[21];
  const float* b2  = (const float*)d_in[22];
  const float* w3  = (const float*)d_in[23];
  const float* b3  = (const float*)d_in[24];

  float* ws    = (float*)d_ws;
  float* hall  = ws;                          // [8][512][192]        =   786,432
  float* At    = hall  + 786432;              // [8][192][192]        =   294,912
  float* xs    = At    + 294912;              // [8][256][192]        =   393,216
  float* rpart = xs    + 393216;              // [8][32][3+7+11][192] = 1,032,192
  float* rbuf  = rpart + 1032192;             // [3][8][11][192]      =    50,688
  float* WXA   = rbuf  + 50688;               // [512]*(12+56+132)    =   102,400
  float* bpA   = WXA   + 102400;              // [3][121]             =       384
  float* cka   = bpA   + 384;                 // [3][11]              =        48
  float* out0  = (float*)d_out;               // [8][256][192]
  float* Aout  = out0 + 8 * 256 * 192;        // [8][192][192]

  // K1: weight folding (wka+wxa fused via LDS row handoff)
  foldw_kernel<<<179, 256, 0, stream>>>(
      wa0, wk0, bk0, wp0, bp0,
      wa1, wk1, bk1, wp1, bp1,
      wa2, wk2, bk2, wp2, bp2,
      WXA, bpA, cka);

  // K2: h1 = w1@x  ||  banded rcomp on x
  k2_kernel<<<96 + 768, 256, 0, stream>>>(x, w1, b1, WXA, hall, rpart);

  // K3: rreduce  ||  grouped conv + relu (h1 -> h2)
  k3_kernel<<<168 + 1536, 256, 0, stream>>>(rpart, cka, bpA, rbuf, w2, b2, hall);

  // K4: softmax A-build (wave-per-column)  ||  xs = w3@h2
  k4_kernel<<<384 + 96, 256, 0, stream>>>(rbuf, ba0, ba1, ba2, At,
                                          hall, w3, b3, xs);

  // K5: out0 = xs@A (transposed At staging)  ||  Aout = At^T
  k5_kernel<<<96 + 288, 256, 0, stream>>>(xs, At, out0, Aout);
}